// Round 1
// baseline (1073.231 us; speedup 1.0000x reference)
//
#include <hip/hip_runtime.h>

#define B_ROWS 32768
#define T_BINS 1024

// ---------------- GEMM (A @ W^T + b) fused with per-row argmax ----------------
// A: [B, T] row-major fp32, W: [T, T] row-major (logits[i,t] = sum_k A[i,k]*W[t,k] + b[t])
// Both operands are K-contiguous ("NT" layout) -> coalesced float4 loads.
#define BM 64
#define BN 64
#define BK 16
#define LDS_STRIDE (BM + 4)   // +4 keeps 16B alignment of float4 LDS reads, breaks pow2 stride

__global__ __launch_bounds__(256) void gemm_argmax_kernel(
    const float* __restrict__ A, const float* __restrict__ W,
    const float* __restrict__ bias, unsigned long long* __restrict__ rec)
{
    __shared__ float As[BK][LDS_STRIDE];
    __shared__ float Ws[BK][LDS_STRIDE];

    const int tid = threadIdx.x;
    const int tx  = tid & 15;      // col group within tile
    const int ty  = tid >> 4;      // row group within tile
    const int bx  = blockIdx.x;    // col tile (over T)
    const int by  = blockIdx.y;    // row tile (over B)

    // staging: each thread loads one float4 of A-tile and one of W-tile
    const int ar = tid >> 2;          // 0..63  (row within tile)
    const int ak = (tid & 3) << 2;    // 0,4,8,12 (k offset)

    const float* Arow = A + (size_t)(by * BM + ar) * T_BINS + ak;
    const float* Wrow = W + (size_t)(bx * BN + ar) * T_BINS + ak;

    float acc[4][4];
#pragma unroll
    for (int i = 0; i < 4; ++i)
#pragma unroll
        for (int j = 0; j < 4; ++j) acc[i][j] = 0.f;

    for (int k0 = 0; k0 < T_BINS; k0 += BK) {
        float4 av = *(const float4*)(Arow + k0);
        float4 wv = *(const float4*)(Wrow + k0);
        As[ak + 0][ar] = av.x; As[ak + 1][ar] = av.y;
        As[ak + 2][ar] = av.z; As[ak + 3][ar] = av.w;
        Ws[ak + 0][ar] = wv.x; Ws[ak + 1][ar] = wv.y;
        Ws[ak + 2][ar] = wv.z; Ws[ak + 3][ar] = wv.w;
        __syncthreads();
#pragma unroll
        for (int k = 0; k < BK; ++k) {
            float4 a4 = *(const float4*)&As[k][ty * 4];
            float4 w4 = *(const float4*)&Ws[k][tx * 4];
            float aa[4] = {a4.x, a4.y, a4.z, a4.w};
            float ww[4] = {w4.x, w4.y, w4.z, w4.w};
#pragma unroll
            for (int i = 0; i < 4; ++i)
#pragma unroll
                for (int j = 0; j < 4; ++j)
                    acc[i][j] = fmaf(aa[i], ww[j], acc[i][j]);
        }
        __syncthreads();
    }

    // add bias, then per-row argmax over this block's 64 columns.
    const int colBase = bx * BN + tx * 4;
    float bv[4];
#pragma unroll
    for (int j = 0; j < 4; ++j) bv[j] = bias[colBase + j];

#pragma unroll
    for (int i = 0; i < 4; ++i) {
        float best = acc[i][0] + bv[0];
        int   bc   = colBase;
#pragma unroll
        for (int j = 1; j < 4; ++j) {
            float v = acc[i][j] + bv[j];
            if (v > best) { best = v; bc = colBase + j; }   // strict > => first index wins
        }
        // reduce across the 16 tx-lanes of this row group (same wave: lanes ty*16+tx)
#pragma unroll
        for (int off = 8; off >= 1; off >>= 1) {
            float ov = __shfl_xor(best, off, 64);
            int   oc = __shfl_xor(bc,   off, 64);
            if (ov > best || (ov == best && oc < bc)) { best = ov; bc = oc; }
        }
        if (tx == 0) {
            // pack (value, ~col): larger value wins; on equal value, smaller col wins.
            unsigned x = __float_as_uint(best);
            x = (x & 0x80000000u) ? ~x : (x | 0x80000000u);
            unsigned long long packed =
                ((unsigned long long)x << 32) | (unsigned)(~bc);
            atomicMax(&rec[by * BM + ty * 4 + i], packed);
        }
    }
}

// ---------------- unpack argmax, write trunc_pos, accumulate MSE ----------------
__global__ __launch_bounds__(256) void finalize_kernel(
    const unsigned long long* __restrict__ rec, const float* __restrict__ labels,
    float* __restrict__ out_trunc, float* __restrict__ loss_acc)
{
    int i = blockIdx.x * 256 + threadIdx.x;
    unsigned col = ~(unsigned)(rec[i] & 0xFFFFFFFFull);
    float p = (float)col;
    out_trunc[i] = p;
    float d = p - labels[i];
    float term = d * d * (1.0f / (float)B_ROWS);   // prescale -> final sum is the mean
#pragma unroll
    for (int off = 32; off >= 1; off >>= 1)
        term += __shfl_down(term, off, 64);
    __shared__ float partials[4];
    int lane = threadIdx.x & 63, wv = threadIdx.x >> 6;
    if (lane == 0) partials[wv] = term;
    __syncthreads();
    if (threadIdx.x == 0) {
        float s = partials[0] + partials[1] + partials[2] + partials[3];
        atomicAdd(loss_acc, s);
    }
}

// ---------------- survival curve: cumprod(1-h) * truncation decay ----------------
__global__ __launch_bounds__(256) void scan_kernel(
    const float* __restrict__ H, const float* __restrict__ trunc_f,
    float* __restrict__ Sout)
{
    __shared__ float sc[256];
    const int row = blockIdx.x;
    const int tid = threadIdx.x;

    const float4 h = *(const float4*)(H + (size_t)row * T_BINS + tid * 4);
    float l0 = 1.f - h.x;
    float l1 = l0 * (1.f - h.y);
    float l2 = l1 * (1.f - h.z);
    float l3 = l2 * (1.f - h.w);

    float x = l3;
    sc[tid] = x;
    __syncthreads();
#pragma unroll
    for (int off = 1; off < 256; off <<= 1) {
        float o = (tid >= off) ? sc[tid - off] : 1.0f;
        __syncthreads();
        x *= o;
        sc[tid] = x;
        __syncthreads();
    }
    float pre = (tid > 0) ? sc[tid - 1] : 1.0f;

    int p  = (int)trunc_f[row];
    int t0 = tid * 4;
    float sv[4] = {pre * l0, pre * l1, pre * l2, pre * l3};
#pragma unroll
    for (int j = 0; j < 4; ++j) {
        int t = t0 + j;
        if (t >= p) sv[j] *= __expf((float)(p - t));
    }
    float4 s4 = {sv[0], sv[1], sv[2], sv[3]};
    *(float4*)(Sout + (size_t)row * T_BINS + tid * 4) = s4;
}

extern "C" void kernel_launch(void* const* d_in, const int* in_sizes, int n_in,
                              void* d_out, int out_size, void* d_ws, size_t ws_size,
                              hipStream_t stream)
{
    const float* hazard = (const float*)d_in[0];   // [B, T]
    const float* labels = (const float*)d_in[1];   // [B]
    const float* W      = (const float*)d_in[2];   // [T, T]
    const float* bias   = (const float*)d_in[3];   // [T]

    float* out       = (float*)d_out;
    float* out_trunc = out;                                       // B floats
    float* out_S     = out + B_ROWS;                              // B*T floats
    float* out_loss  = out + B_ROWS + (size_t)B_ROWS * T_BINS;    // 1 float

    // argmax records live in the first 64 rows of the S region; scan_kernel
    // overwrites them last (kernels on one stream serialize), so no d_ws needed.
    unsigned long long* rec = (unsigned long long*)out_S;

    hipMemsetAsync(rec, 0, (size_t)B_ROWS * sizeof(unsigned long long), stream);
    hipMemsetAsync(out_loss, 0, sizeof(float), stream);

    dim3 ggrid(T_BINS / BN, B_ROWS / BM);   // (16, 512)
    gemm_argmax_kernel<<<ggrid, 256, 0, stream>>>(hazard, W, bias, rec);
    finalize_kernel<<<B_ROWS / 256, 256, 0, stream>>>(rec, labels, out_trunc, out_loss);
    scan_kernel<<<B_ROWS, 256, 0, stream>>>(hazard, out_trunc, out_S);
}

// Round 2
// 502.759 us; speedup vs baseline: 2.1347x; 2.1347x over previous
//
#include <hip/hip_runtime.h>

#define B_ROWS 32768
#define T_BINS 1024

typedef __attribute__((ext_vector_type(8))) short short8;
typedef __attribute__((ext_vector_type(4))) float floatx4;

__device__ __forceinline__ unsigned long long pack_max(float v, int col) {
    unsigned x = __float_as_uint(v);
    x = (x & 0x80000000u) ? ~x : (x | 0x80000000u);   // monotone float->uint
    return ((unsigned long long)x << 32) | (unsigned)(~col);  // ties -> smaller col
}

__device__ __forceinline__ void async16(const unsigned short* g, unsigned short* l) {
    __builtin_amdgcn_global_load_lds(
        (const __attribute__((address_space(1))) unsigned int*)g,
        (__attribute__((address_space(3))) unsigned int*)l,
        16, 0, 0);
}

// ---------------- split fp32 -> (hi, lo) bf16 planes (truncation split) ----------------
__global__ __launch_bounds__(256) void split_kernel(
    const float* __restrict__ src, unsigned short* __restrict__ hi,
    unsigned short* __restrict__ lo, int n4)
{
    int idx = blockIdx.x * 256 + threadIdx.x;
    if (idx >= n4) return;
    float4 x = ((const float4*)src)[idx];
    ushort4 h, l;
    {
        unsigned u = __float_as_uint(x.x); h.x = (unsigned short)(u >> 16);
        float r = x.x - __uint_as_float(u & 0xFFFF0000u);
        l.x = (unsigned short)(__float_as_uint(r) >> 16);
    }
    {
        unsigned u = __float_as_uint(x.y); h.y = (unsigned short)(u >> 16);
        float r = x.y - __uint_as_float(u & 0xFFFF0000u);
        l.y = (unsigned short)(__float_as_uint(r) >> 16);
    }
    {
        unsigned u = __float_as_uint(x.z); h.z = (unsigned short)(u >> 16);
        float r = x.z - __uint_as_float(u & 0xFFFF0000u);
        l.z = (unsigned short)(__float_as_uint(r) >> 16);
    }
    {
        unsigned u = __float_as_uint(x.w); h.w = (unsigned short)(u >> 16);
        float r = x.w - __uint_as_float(u & 0xFFFF0000u);
        l.w = (unsigned short)(__float_as_uint(r) >> 16);
    }
    ((ushort4*)hi)[idx] = h;
    ((ushort4*)lo)[idx] = l;
}

// ---------------- MFMA GEMM (split-bf16) fused with per-row argmax ----------------
// logits[i,t] = sum_k A[i,k]*W[t,k] + b[t];  A',W' are bf16 hi/lo planes, K-contiguous (NT).
// 128x128 tile, BK=32, 4 waves in 2x2, each wave 64x64 via 4x4 frags of 16x16x32.
__global__ __launch_bounds__(256) void gemm_mfma_argmax(
    const unsigned short* __restrict__ Ahi_g, const unsigned short* __restrict__ Alo_g,
    const unsigned short* __restrict__ Whi_g, const unsigned short* __restrict__ Wlo_g,
    const float* __restrict__ bias, unsigned long long* __restrict__ rec)
{
    __shared__ unsigned short sAhi[128 * 32];
    __shared__ unsigned short sAlo[128 * 32];
    __shared__ unsigned short sWhi[128 * 32];
    __shared__ unsigned short sWlo[128 * 32];

    const int tid  = threadIdx.x;
    const int lane = tid & 63;
    const int wv   = tid >> 6;
    const int wr   = wv >> 1;     // wave row: 0..1
    const int wc   = wv & 1;      // wave col: 0..1
    const int bx   = blockIdx.x;  // col tile over T: 0..7
    const int by   = blockIdx.y;  // row tile over B: 0..255

    const int rowA = by * 128;
    const int rowW = bx * 128;

    floatx4 acc[4][4];
#pragma unroll
    for (int i = 0; i < 4; ++i)
#pragma unroll
        for (int j = 0; j < 4; ++j) acc[i][j] = (floatx4){0.f, 0.f, 0.f, 0.f};

    // staging: chunk c = round*256 + tid; LDS offset c*16B; row = c>>2, kchunk = c&3
    const int c0 = tid, c1 = 256 + tid;
    const int r0 = c0 >> 2, kc0 = (c0 & 3) * 8;
    const int r1 = c1 >> 2, kc1 = (c1 & 3) * 8;
    const int ub0 = (wv * 64) * 8;          // wave-uniform LDS base (shorts), round 0
    const int ub1 = (256 + wv * 64) * 8;    // round 1

    const size_t a0 = (size_t)(rowA + r0) * T_BINS + kc0;
    const size_t a1 = (size_t)(rowA + r1) * T_BINS + kc1;
    const size_t w0 = (size_t)(rowW + r0) * T_BINS + kc0;
    const size_t w1 = (size_t)(rowW + r1) * T_BINS + kc1;

    const int ko = (lane >> 4) * 8;         // k-offset of this lane's fragment

    for (int k0 = 0; k0 < T_BINS; k0 += 32) {
        async16(Ahi_g + a0 + k0, &sAhi[ub0]);
        async16(Ahi_g + a1 + k0, &sAhi[ub1]);
        async16(Alo_g + a0 + k0, &sAlo[ub0]);
        async16(Alo_g + a1 + k0, &sAlo[ub1]);
        async16(Whi_g + w0 + k0, &sWhi[ub0]);
        async16(Whi_g + w1 + k0, &sWhi[ub1]);
        async16(Wlo_g + w0 + k0, &sWlo[ub0]);
        async16(Wlo_g + w1 + k0, &sWlo[ub1]);
        asm volatile("s_waitcnt vmcnt(0)" ::: "memory");
        __syncthreads();

        short8 ah[4], al[4], wh[4], wl[4];
#pragma unroll
        for (int i = 0; i < 4; ++i) {
            int ra = (wr * 64 + i * 16 + (lane & 15)) * 32 + ko;
            int rw = (wc * 64 + i * 16 + (lane & 15)) * 32 + ko;
            ah[i] = *(const short8*)&sAhi[ra];
            al[i] = *(const short8*)&sAlo[ra];
            wh[i] = *(const short8*)&sWhi[rw];
            wl[i] = *(const short8*)&sWlo[rw];
        }
#pragma unroll
        for (int i = 0; i < 4; ++i)
#pragma unroll
            for (int j = 0; j < 4; ++j) {
                acc[i][j] = __builtin_amdgcn_mfma_f32_16x16x32_bf16(ah[i], wh[j], acc[i][j], 0, 0, 0);
                acc[i][j] = __builtin_amdgcn_mfma_f32_16x16x32_bf16(ah[i], wl[j], acc[i][j], 0, 0, 0);
                acc[i][j] = __builtin_amdgcn_mfma_f32_16x16x32_bf16(al[i], wh[j], acc[i][j], 0, 0, 0);
            }
        __syncthreads();
    }

    // epilogue: bias + per-row argmax over this block's 128 cols.
    // C/D layout: col = lane&15 (+j*16 +wc*64), row = (lane>>4)*4 + reg (+i*16 +wr*64)
    const int colbase = bx * 128 + wc * 64 + (lane & 15);
    float bj[4];
#pragma unroll
    for (int j = 0; j < 4; ++j) bj[j] = bias[colbase + j * 16];

#pragma unroll
    for (int i = 0; i < 4; ++i) {
#pragma unroll
        for (int r = 0; r < 4; ++r) {
            float best = acc[i][0][r] + bj[0];
            int   bc   = colbase;
#pragma unroll
            for (int j = 1; j < 4; ++j) {
                float v = acc[i][j][r] + bj[j];
                if (v > best) { best = v; bc = colbase + j * 16; }  // strict >: first idx wins
            }
#pragma unroll
            for (int off = 8; off >= 1; off >>= 1) {   // reduce over the 16 col-lanes
                float ov = __shfl_xor(best, off, 64);
                int   oc = __shfl_xor(bc, off, 64);
                if (ov > best || (ov == best && oc < bc)) { best = ov; bc = oc; }
            }
            if ((lane & 15) == 0) {
                int rowG = by * 128 + wr * 64 + i * 16 + (lane >> 4) * 4 + r;
                atomicMax(&rec[rowG], pack_max(best, bc));
            }
        }
    }
}

// ---------------- fp32 fallback GEMM (round-1 kernel), used if ws too small ----------------
#define BMf 64
#define BKf 16
#define LDSS (BMf + 4)
__global__ __launch_bounds__(256) void gemm_argmax_fp32(
    const float* __restrict__ A, const float* __restrict__ W,
    const float* __restrict__ bias, unsigned long long* __restrict__ rec)
{
    __shared__ float As[BKf][LDSS];
    __shared__ float Ws[BKf][LDSS];
    const int tid = threadIdx.x;
    const int tx = tid & 15, ty = tid >> 4;
    const int bx = blockIdx.x, by = blockIdx.y;
    const int ar = tid >> 2, ak = (tid & 3) << 2;
    const float* Arow = A + (size_t)(by * BMf + ar) * T_BINS + ak;
    const float* Wrow = W + (size_t)(bx * BMf + ar) * T_BINS + ak;
    float acc[4][4];
#pragma unroll
    for (int i = 0; i < 4; ++i)
#pragma unroll
        for (int j = 0; j < 4; ++j) acc[i][j] = 0.f;
    for (int k0 = 0; k0 < T_BINS; k0 += BKf) {
        float4 av = *(const float4*)(Arow + k0);
        float4 wvv = *(const float4*)(Wrow + k0);
        As[ak + 0][ar] = av.x; As[ak + 1][ar] = av.y; As[ak + 2][ar] = av.z; As[ak + 3][ar] = av.w;
        Ws[ak + 0][ar] = wvv.x; Ws[ak + 1][ar] = wvv.y; Ws[ak + 2][ar] = wvv.z; Ws[ak + 3][ar] = wvv.w;
        __syncthreads();
#pragma unroll
        for (int k = 0; k < BKf; ++k) {
            float4 a4 = *(const float4*)&As[k][ty * 4];
            float4 w4 = *(const float4*)&Ws[k][tx * 4];
            float aa[4] = {a4.x, a4.y, a4.z, a4.w};
            float ww[4] = {w4.x, w4.y, w4.z, w4.w};
#pragma unroll
            for (int i = 0; i < 4; ++i)
#pragma unroll
                for (int j = 0; j < 4; ++j) acc[i][j] = fmaf(aa[i], ww[j], acc[i][j]);
        }
        __syncthreads();
    }
    const int colBase = bx * BMf + tx * 4;
    float bv[4];
#pragma unroll
    for (int j = 0; j < 4; ++j) bv[j] = bias[colBase + j];
#pragma unroll
    for (int i = 0; i < 4; ++i) {
        float best = acc[i][0] + bv[0];
        int bc = colBase;
#pragma unroll
        for (int j = 1; j < 4; ++j) {
            float v = acc[i][j] + bv[j];
            if (v > best) { best = v; bc = colBase + j; }
        }
#pragma unroll
        for (int off = 8; off >= 1; off >>= 1) {
            float ov = __shfl_xor(best, off, 64);
            int oc = __shfl_xor(bc, off, 64);
            if (ov > best || (ov == best && oc < bc)) { best = ov; bc = oc; }
        }
        if (tx == 0) atomicMax(&rec[by * BMf + ty * 4 + i], pack_max(best, bc));
    }
}

// ---------------- unpack argmax, write trunc_pos, accumulate MSE ----------------
__global__ __launch_bounds__(256) void finalize_kernel(
    const unsigned long long* __restrict__ rec, const float* __restrict__ labels,
    float* __restrict__ out_trunc, float* __restrict__ loss_acc)
{
    int i = blockIdx.x * 256 + threadIdx.x;
    unsigned col = ~(unsigned)(rec[i] & 0xFFFFFFFFull);
    float p = (float)col;
    out_trunc[i] = p;
    float d = p - labels[i];
    float term = d * d * (1.0f / (float)B_ROWS);
#pragma unroll
    for (int off = 32; off >= 1; off >>= 1)
        term += __shfl_down(term, off, 64);
    __shared__ float partials[4];
    int lane = threadIdx.x & 63, wv = threadIdx.x >> 6;
    if (lane == 0) partials[wv] = term;
    __syncthreads();
    if (threadIdx.x == 0)
        atomicAdd(loss_acc, partials[0] + partials[1] + partials[2] + partials[3]);
}

// ---------------- survival curve: cumprod(1-h) * decay, barrier-light wave scan ----------------
__global__ __launch_bounds__(256) void scan_kernel(
    const float* __restrict__ H, const float* __restrict__ trunc_f,
    float* __restrict__ Sout)
{
    const int row = blockIdx.x;
    const int tid = threadIdx.x;
    const int lane = tid & 63;
    const int wv = tid >> 6;

    const float4 h = *(const float4*)(H + (size_t)row * T_BINS + tid * 4);
    float l0 = 1.f - h.x;
    float l1 = l0 * (1.f - h.y);
    float l2 = l1 * (1.f - h.z);
    float l3 = l2 * (1.f - h.w);

    // inclusive wave scan (product) of per-thread totals
    float x = l3;
#pragma unroll
    for (int off = 1; off < 64; off <<= 1) {
        float o = __shfl_up(x, off, 64);
        if (lane >= off) x *= o;
    }
    float ex = __shfl_up(x, 1, 64);
    if (lane == 0) ex = 1.f;

    __shared__ float wtot[4];
    if (lane == 63) wtot[wv] = x;
    __syncthreads();
    float wpre = 1.f;
#pragma unroll
    for (int w = 0; w < 3; ++w)
        if (w < wv) wpre *= wtot[w];
    float pre = wpre * ex;

    int p = (int)trunc_f[row];
    int t0 = tid * 4;
    float sv[4] = {pre * l0, pre * l1, pre * l2, pre * l3};
#pragma unroll
    for (int j = 0; j < 4; ++j) {
        int t = t0 + j;
        if (t >= p) sv[j] *= __expf((float)(p - t));
    }
    float4 s4 = {sv[0], sv[1], sv[2], sv[3]};
    *(float4*)(Sout + (size_t)row * T_BINS + tid * 4) = s4;
}

extern "C" void kernel_launch(void* const* d_in, const int* in_sizes, int n_in,
                              void* d_out, int out_size, void* d_ws, size_t ws_size,
                              hipStream_t stream)
{
    const float* hazard = (const float*)d_in[0];   // [B, T]
    const float* labels = (const float*)d_in[1];   // [B]
    const float* W      = (const float*)d_in[2];   // [T, T]
    const float* bias   = (const float*)d_in[3];   // [T]

    float* out       = (float*)d_out;
    float* out_trunc = out;                                       // B floats
    float* out_S     = out + B_ROWS;                              // B*T floats
    float* out_loss  = out + B_ROWS + (size_t)B_ROWS * T_BINS;    // 1 float

    // argmax records live at the head of the S region; scan_kernel overwrites them last.
    unsigned long long* rec = (unsigned long long*)out_S;

    hipMemsetAsync(rec, 0, (size_t)B_ROWS * sizeof(unsigned long long), stream);
    hipMemsetAsync(out_loss, 0, sizeof(float), stream);

    const size_t NA = (size_t)B_ROWS * T_BINS;
    const size_t NW = (size_t)T_BINS * T_BINS;
    const size_t need = (NA + NW) * 2 * sizeof(unsigned short);   // ~138 MB

    if (ws_size >= need) {
        unsigned short* Ahi = (unsigned short*)d_ws;
        unsigned short* Alo = Ahi + NA;
        unsigned short* Whi = Alo + NA;
        unsigned short* Wlo = Whi + NW;
        split_kernel<<<(int)(NA / 4 / 256), 256, 0, stream>>>(hazard, Ahi, Alo, (int)(NA / 4));
        split_kernel<<<(int)(NW / 4 / 256), 256, 0, stream>>>(W, Whi, Wlo, (int)(NW / 4));
        dim3 ggrid(T_BINS / 128, B_ROWS / 128);   // (8, 256)
        gemm_mfma_argmax<<<ggrid, 256, 0, stream>>>(Ahi, Alo, Whi, Wlo, bias, rec);
    } else {
        dim3 ggrid(T_BINS / BMf, B_ROWS / BMf);   // (16, 512)
        gemm_argmax_fp32<<<ggrid, 256, 0, stream>>>(hazard, W, bias, rec);
    }
    finalize_kernel<<<B_ROWS / 256, 256, 0, stream>>>(rec, labels, out_trunc, out_loss);
    scan_kernel<<<B_ROWS, 256, 0, stream>>>(hazard, out_trunc, out_S);
}

// Round 3
// 386.064 us; speedup vs baseline: 2.7799x; 1.3023x over previous
//
#include <hip/hip_runtime.h>

#define B_ROWS 32768
#define T_BINS 1024

typedef __attribute__((ext_vector_type(8))) _Float16 half8;
typedef __attribute__((ext_vector_type(4))) float floatx4;

__device__ __forceinline__ unsigned long long pack_max(float v, int col) {
    unsigned x = __float_as_uint(v);
    x = (x & 0x80000000u) ? ~x : (x | 0x80000000u);   // monotone float->uint
    return ((unsigned long long)x << 32) | (unsigned)(~col);  // ties -> smaller col
}

__device__ __forceinline__ void async16(const _Float16* g, _Float16* l) {
    __builtin_amdgcn_global_load_lds(
        (const __attribute__((address_space(1))) unsigned int*)g,
        (__attribute__((address_space(3))) unsigned int*)l,
        16, 0, 0);
}

// ---------------- convert fp32 -> f16 plane (RTN) ----------------
__global__ __launch_bounds__(256) void tof16_kernel(
    const float* __restrict__ src, _Float16* __restrict__ dst, int n4)
{
    int idx = blockIdx.x * 256 + threadIdx.x;
    if (idx >= n4) return;
    float4 x = ((const float4*)src)[idx];
    union { _Float16 h[4]; ushort4 u; } cv;
    cv.h[0] = (_Float16)x.x;
    cv.h[1] = (_Float16)x.y;
    cv.h[2] = (_Float16)x.z;
    cv.h[3] = (_Float16)x.w;
    ((ushort4*)dst)[idx] = cv.u;
}

// ---------------- MFMA f16 GEMM fused with per-row argmax ----------------
// logits[i,t] = sum_k A[i,k]*W[t,k] + b[t]; A,W f16 planes, K-contiguous (NT).
// 128x128 tile, BK=32, 4 waves in 2x2, each wave 64x64 via 4x4 frags of 16x16x32.
__global__ __launch_bounds__(256) void gemm_f16_argmax(
    const _Float16* __restrict__ Ag, const _Float16* __restrict__ Wg,
    const float* __restrict__ bias, unsigned long long* __restrict__ rec)
{
    __shared__ _Float16 sA[128 * 32];
    __shared__ _Float16 sW[128 * 32];

    const int tid  = threadIdx.x;
    const int lane = tid & 63;
    const int wv   = tid >> 6;
    const int wr   = wv >> 1;     // wave row: 0..1
    const int wc   = wv & 1;      // wave col: 0..1
    const int bx   = blockIdx.x;  // col tile over T: 0..7
    const int by   = blockIdx.y;  // row tile over B: 0..255

    floatx4 acc[4][4];
#pragma unroll
    for (int i = 0; i < 4; ++i)
#pragma unroll
        for (int j = 0; j < 4; ++j) acc[i][j] = (floatx4){0.f, 0.f, 0.f, 0.f};

    // staging: chunk c = round*256 + tid; LDS offset c*16B; row = c>>2, kchunk = c&3
    const int c0 = tid, c1 = 256 + tid;
    const int r0 = c0 >> 2, kc0 = (c0 & 3) * 8;
    const int r1 = c1 >> 2, kc1 = (c1 & 3) * 8;
    const int ub0 = (wv * 64) * 8;          // wave-uniform LDS base (halves), round 0
    const int ub1 = (256 + wv * 64) * 8;    // round 1

    const size_t a0 = (size_t)(by * 128 + r0) * T_BINS + kc0;
    const size_t a1 = (size_t)(by * 128 + r1) * T_BINS + kc1;
    const size_t w0 = (size_t)(bx * 128 + r0) * T_BINS + kc0;
    const size_t w1 = (size_t)(bx * 128 + r1) * T_BINS + kc1;

    const int ko = (lane >> 4) * 8;         // k-offset of this lane's fragment

    for (int k0 = 0; k0 < T_BINS; k0 += 32) {
        async16(Ag + a0 + k0, &sA[ub0]);
        async16(Ag + a1 + k0, &sA[ub1]);
        async16(Wg + w0 + k0, &sW[ub0]);
        async16(Wg + w1 + k0, &sW[ub1]);
        asm volatile("s_waitcnt vmcnt(0)" ::: "memory");
        __syncthreads();

        half8 ah[4], wh[4];
#pragma unroll
        for (int i = 0; i < 4; ++i) {
            int ra = (wr * 64 + i * 16 + (lane & 15)) * 32 + ko;
            int rw = (wc * 64 + i * 16 + (lane & 15)) * 32 + ko;
            ah[i] = *(const half8*)&sA[ra];
            wh[i] = *(const half8*)&sW[rw];
        }
#pragma unroll
        for (int i = 0; i < 4; ++i)
#pragma unroll
            for (int j = 0; j < 4; ++j)
                acc[i][j] = __builtin_amdgcn_mfma_f32_16x16x32_f16(ah[i], wh[j], acc[i][j], 0, 0, 0);
        __syncthreads();
    }

    // epilogue: bias + per-row argmax over this block's 128 cols.
    // C/D layout: col = lane&15 (+j*16 +wc*64), row = (lane>>4)*4 + reg (+i*16 +wr*64)
    const int colbase = bx * 128 + wc * 64 + (lane & 15);
    float bj[4];
#pragma unroll
    for (int j = 0; j < 4; ++j) bj[j] = bias[colbase + j * 16];

#pragma unroll
    for (int i = 0; i < 4; ++i) {
#pragma unroll
        for (int r = 0; r < 4; ++r) {
            float best = acc[i][0][r] + bj[0];
            int   bc   = colbase;
#pragma unroll
            for (int j = 1; j < 4; ++j) {
                float v = acc[i][j][r] + bj[j];
                if (v > best) { best = v; bc = colbase + j * 16; }  // strict >: first idx wins
            }
#pragma unroll
            for (int off = 8; off >= 1; off >>= 1) {   // reduce over the 16 col-lanes
                float ov = __shfl_xor(best, off, 64);
                int   oc = __shfl_xor(bc, off, 64);
                if (ov > best || (ov == best && oc < bc)) { best = ov; bc = oc; }
            }
            if ((lane & 15) == 0) {
                int rowG = by * 128 + wr * 64 + i * 16 + (lane >> 4) * 4 + r;
                atomicMax(&rec[rowG], pack_max(best, bc));
            }
        }
    }
}

// ---------------- fp32 fallback GEMM (round-1 kernel), used if ws too small ----------------
#define BMf 64
#define BKf 16
#define LDSS (BMf + 4)
__global__ __launch_bounds__(256) void gemm_argmax_fp32(
    const float* __restrict__ A, const float* __restrict__ W,
    const float* __restrict__ bias, unsigned long long* __restrict__ rec)
{
    __shared__ float As[BKf][LDSS];
    __shared__ float Ws[BKf][LDSS];
    const int tid = threadIdx.x;
    const int tx = tid & 15, ty = tid >> 4;
    const int bx = blockIdx.x, by = blockIdx.y;
    const int ar = tid >> 2, ak = (tid & 3) << 2;
    const float* Arow = A + (size_t)(by * BMf + ar) * T_BINS + ak;
    const float* Wrow = W + (size_t)(bx * BMf + ar) * T_BINS + ak;
    float acc[4][4];
#pragma unroll
    for (int i = 0; i < 4; ++i)
#pragma unroll
        for (int j = 0; j < 4; ++j) acc[i][j] = 0.f;
    for (int k0 = 0; k0 < T_BINS; k0 += BKf) {
        float4 av = *(const float4*)(Arow + k0);
        float4 wvv = *(const float4*)(Wrow + k0);
        As[ak + 0][ar] = av.x; As[ak + 1][ar] = av.y; As[ak + 2][ar] = av.z; As[ak + 3][ar] = av.w;
        Ws[ak + 0][ar] = wvv.x; Ws[ak + 1][ar] = wvv.y; Ws[ak + 2][ar] = wvv.z; Ws[ak + 3][ar] = wvv.w;
        __syncthreads();
#pragma unroll
        for (int k = 0; k < BKf; ++k) {
            float4 a4 = *(const float4*)&As[k][ty * 4];
            float4 w4 = *(const float4*)&Ws[k][tx * 4];
            float aa[4] = {a4.x, a4.y, a4.z, a4.w};
            float ww[4] = {w4.x, w4.y, w4.z, w4.w};
#pragma unroll
            for (int i = 0; i < 4; ++i)
#pragma unroll
                for (int j = 0; j < 4; ++j) acc[i][j] = fmaf(aa[i], ww[j], acc[i][j]);
        }
        __syncthreads();
    }
    const int colBase = bx * BMf + tx * 4;
    float bv[4];
#pragma unroll
    for (int j = 0; j < 4; ++j) bv[j] = bias[colBase + j];
#pragma unroll
    for (int i = 0; i < 4; ++i) {
        float best = acc[i][0] + bv[0];
        int bc = colBase;
#pragma unroll
        for (int j = 1; j < 4; ++j) {
            float v = acc[i][j] + bv[j];
            if (v > best) { best = v; bc = colBase + j; }
        }
#pragma unroll
        for (int off = 8; off >= 1; off >>= 1) {
            float ov = __shfl_xor(best, off, 64);
            int oc = __shfl_xor(bc, off, 64);
            if (ov > best || (ov == best && oc < bc)) { best = ov; bc = oc; }
        }
        if (tx == 0) atomicMax(&rec[by * BMf + ty * 4 + i], pack_max(best, bc));
    }
}

// ---------------- unpack argmax, write trunc_pos, accumulate MSE ----------------
__global__ __launch_bounds__(256) void finalize_kernel(
    const unsigned long long* __restrict__ rec, const float* __restrict__ labels,
    float* __restrict__ out_trunc, float* __restrict__ loss_acc)
{
    int i = blockIdx.x * 256 + threadIdx.x;
    unsigned col = ~(unsigned)(rec[i] & 0xFFFFFFFFull);
    float p = (float)col;
    out_trunc[i] = p;
    float d = p - labels[i];
    float term = d * d * (1.0f / (float)B_ROWS);
#pragma unroll
    for (int off = 32; off >= 1; off >>= 1)
        term += __shfl_down(term, off, 64);
    __shared__ float partials[4];
    int lane = threadIdx.x & 63, wv = threadIdx.x >> 6;
    if (lane == 0) partials[wv] = term;
    __syncthreads();
    if (threadIdx.x == 0)
        atomicAdd(loss_acc, partials[0] + partials[1] + partials[2] + partials[3]);
}

// ---------------- survival curve from the f16 plane: cumprod(1-h) * decay ----------------
__global__ __launch_bounds__(256) void scan_kernel_f16(
    const _Float16* __restrict__ Hh, const float* __restrict__ trunc_f,
    float* __restrict__ Sout)
{
    const int row = blockIdx.x;
    const int tid = threadIdx.x;
    const int lane = tid & 63;
    const int wv = tid >> 6;

    union { ushort4 u; _Float16 h[4]; } cv;
    cv.u = ((const ushort4*)Hh)[(size_t)row * (T_BINS / 4) + tid];
    float l0 = 1.f - (float)cv.h[0];
    float l1 = l0 * (1.f - (float)cv.h[1]);
    float l2 = l1 * (1.f - (float)cv.h[2]);
    float l3 = l2 * (1.f - (float)cv.h[3]);

    // inclusive wave scan (product) of per-thread totals
    float x = l3;
#pragma unroll
    for (int off = 1; off < 64; off <<= 1) {
        float o = __shfl_up(x, off, 64);
        if (lane >= off) x *= o;
    }
    float ex = __shfl_up(x, 1, 64);
    if (lane == 0) ex = 1.f;

    __shared__ float wtot[4];
    if (lane == 63) wtot[wv] = x;
    __syncthreads();
    float wpre = 1.f;
#pragma unroll
    for (int w = 0; w < 3; ++w)
        if (w < wv) wpre *= wtot[w];
    float pre = wpre * ex;

    int p = (int)trunc_f[row];
    int t0 = tid * 4;
    float sv[4] = {pre * l0, pre * l1, pre * l2, pre * l3};
#pragma unroll
    for (int j = 0; j < 4; ++j) {
        int t = t0 + j;
        if (t >= p) sv[j] *= __expf((float)(p - t));
    }
    float4 s4 = {sv[0], sv[1], sv[2], sv[3]};
    *(float4*)(Sout + (size_t)row * T_BINS + tid * 4) = s4;
}

// ---------------- fp32 scan fallback ----------------
__global__ __launch_bounds__(256) void scan_kernel_f32(
    const float* __restrict__ H, const float* __restrict__ trunc_f,
    float* __restrict__ Sout)
{
    const int row = blockIdx.x;
    const int tid = threadIdx.x;
    const int lane = tid & 63;
    const int wv = tid >> 6;
    const float4 h = *(const float4*)(H + (size_t)row * T_BINS + tid * 4);
    float l0 = 1.f - h.x;
    float l1 = l0 * (1.f - h.y);
    float l2 = l1 * (1.f - h.z);
    float l3 = l2 * (1.f - h.w);
    float x = l3;
#pragma unroll
    for (int off = 1; off < 64; off <<= 1) {
        float o = __shfl_up(x, off, 64);
        if (lane >= off) x *= o;
    }
    float ex = __shfl_up(x, 1, 64);
    if (lane == 0) ex = 1.f;
    __shared__ float wtot[4];
    if (lane == 63) wtot[wv] = x;
    __syncthreads();
    float wpre = 1.f;
#pragma unroll
    for (int w = 0; w < 3; ++w)
        if (w < wv) wpre *= wtot[w];
    float pre = wpre * ex;
    int p = (int)trunc_f[row];
    int t0 = tid * 4;
    float sv[4] = {pre * l0, pre * l1, pre * l2, pre * l3};
#pragma unroll
    for (int j = 0; j < 4; ++j) {
        int t = t0 + j;
        if (t >= p) sv[j] *= __expf((float)(p - t));
    }
    float4 s4 = {sv[0], sv[1], sv[2], sv[3]};
    *(float4*)(Sout + (size_t)row * T_BINS + tid * 4) = s4;
}

extern "C" void kernel_launch(void* const* d_in, const int* in_sizes, int n_in,
                              void* d_out, int out_size, void* d_ws, size_t ws_size,
                              hipStream_t stream)
{
    const float* hazard = (const float*)d_in[0];   // [B, T]
    const float* labels = (const float*)d_in[1];   // [B]
    const float* W      = (const float*)d_in[2];   // [T, T]
    const float* bias   = (const float*)d_in[3];   // [T]

    float* out       = (float*)d_out;
    float* out_trunc = out;                                       // B floats
    float* out_S     = out + B_ROWS;                              // B*T floats
    float* out_loss  = out + B_ROWS + (size_t)B_ROWS * T_BINS;    // 1 float

    // argmax records live at the head of the S region; scan overwrites them last.
    unsigned long long* rec = (unsigned long long*)out_S;

    hipMemsetAsync(rec, 0, (size_t)B_ROWS * sizeof(unsigned long long), stream);
    hipMemsetAsync(out_loss, 0, sizeof(float), stream);

    const size_t NA = (size_t)B_ROWS * T_BINS;
    const size_t NW = (size_t)T_BINS * T_BINS;
    const size_t need = (NA + NW) * sizeof(_Float16);   // ~69 MB

    if (ws_size >= need) {
        _Float16* Ah = (_Float16*)d_ws;
        _Float16* Wh = Ah + NA;
        tof16_kernel<<<(int)(NA / 4 / 256), 256, 0, stream>>>(hazard, Ah, (int)(NA / 4));
        tof16_kernel<<<(int)(NW / 4 / 256), 256, 0, stream>>>(W, Wh, (int)(NW / 4));
        dim3 ggrid(T_BINS / 128, B_ROWS / 128);   // (8, 256)
        gemm_f16_argmax<<<ggrid, 256, 0, stream>>>(Ah, Wh, bias, rec);
        finalize_kernel<<<B_ROWS / 256, 256, 0, stream>>>(rec, labels, out_trunc, out_loss);
        scan_kernel_f16<<<B_ROWS, 256, 0, stream>>>(Ah, out_trunc, out_S);
    } else {
        dim3 ggrid(T_BINS / BMf, B_ROWS / BMf);   // (16, 512)
        gemm_argmax_fp32<<<ggrid, 256, 0, stream>>>(hazard, W, bias, rec);
        finalize_kernel<<<B_ROWS / 256, 256, 0, stream>>>(rec, labels, out_trunc, out_loss);
        scan_kernel_f32<<<B_ROWS, 256, 0, stream>>>(hazard, out_trunc, out_S);
    }
}

// Round 4
// 379.549 us; speedup vs baseline: 2.8276x; 1.0172x over previous
//
#include <hip/hip_runtime.h>

#define B_ROWS 32768
#define T_BINS 1024

typedef __attribute__((ext_vector_type(8))) _Float16 half8;
typedef __attribute__((ext_vector_type(4))) float floatx4;

__device__ __forceinline__ unsigned long long pack_max(float v, int col) {
    unsigned x = __float_as_uint(v);
    x = (x & 0x80000000u) ? ~x : (x | 0x80000000u);   // monotone float->uint
    return ((unsigned long long)x << 32) | (unsigned)(~col);  // ties -> smaller col
}

__device__ __forceinline__ void async16h(const _Float16* g, _Float16* l) {
    __builtin_amdgcn_global_load_lds(
        (const __attribute__((address_space(1))) unsigned int*)g,
        (__attribute__((address_space(3))) unsigned int*)l,
        16, 0, 0);
}

// ---------------- convert fp32 -> f16 (RNE), used for W only ----------------
__global__ __launch_bounds__(256) void tof16_kernel(
    const float* __restrict__ src, _Float16* __restrict__ dst, int n4)
{
    int idx = blockIdx.x * 256 + threadIdx.x;
    if (idx >= n4) return;
    float4 x = ((const float4*)src)[idx];
    union { _Float16 h[4]; ushort4 u; } cv;
    cv.h[0] = (_Float16)x.x;
    cv.h[1] = (_Float16)x.y;
    cv.h[2] = (_Float16)x.z;
    cv.h[3] = (_Float16)x.w;
    ((ushort4*)dst)[idx] = cv.u;
}

// ---------------- MEGA: GEMM+argmax (full row per block) + loss + scan ----------------
// Block owns 64 rows. Loops bx=0..3 over 256-col slices (N=1024 total) so the
// full-row argmax is block-local: no cross-block atomics, no separate finalize,
// and the same block then computes S = cumprod(1-h)*decay for its rows (fp32 H).
// A converted fp32->f16 in-register at staging; W pre-converted (f16 in d_ws).
__global__ __launch_bounds__(256, 2) void mega_kernel(
    const float* __restrict__ A, const _Float16* __restrict__ Wh,
    const float* __restrict__ bias, const float* __restrict__ labels,
    float* __restrict__ out_trunc, float* __restrict__ out_S,
    float* __restrict__ loss_acc)
{
    __shared__ _Float16 sA[64 * 32];    // [row][k] halves, 64B row stride (m97 layout)
    __shared__ _Float16 sW[256 * 32];
    __shared__ unsigned long long cand[4][64];
    __shared__ float trunc_s[64];

    const int tid  = threadIdx.x;
    const int lane = tid & 63;
    const int wc   = tid >> 6;      // wave = column group 0..3
    const int by   = blockIdx.x;    // row slab 0..511

    // A staging (register path): thread -> (row=tid>>2, kgroup=(tid&3)*8)
    const int arow = tid >> 2;
    const int akg  = (tid & 3) * 8;
    const float* Abase = A + (size_t)(by * 64 + arow) * T_BINS + akg;
    _Float16* sAdst = &sA[arow * 32 + akg];

    // W staging via async16: chunk c=r*256+tid -> row=c>>2, koff=(c&3)*8
    const int ko = (lane >> 4) * 8;

    float run_best[4][4];
    int   run_col[4][4];
#pragma unroll
    for (int i = 0; i < 4; ++i)
#pragma unroll
        for (int r = 0; r < 4; ++r) { run_best[i][r] = -3.4e38f; run_col[i][r] = 0; }

    // prologue A prefetch (k0 = 0); k-wrap makes the last prefetch of each bx
    // exactly the first tile of the next bx (A is bx-independent).
    float4 pa0 = *(const float4*)(Abase);
    float4 pa1 = *(const float4*)(Abase + 4);

    for (int bx = 0; bx < 4; ++bx) {
        const int colbase = bx * 256 + wc * 64 + (lane & 15);
        float bj[4];
#pragma unroll
        for (int j = 0; j < 4; ++j) bj[j] = bias[colbase + j * 16];

        floatx4 acc[4][4];
#pragma unroll
        for (int i = 0; i < 4; ++i)
#pragma unroll
            for (int j = 0; j < 4; ++j) acc[i][j] = (floatx4){0.f, 0.f, 0.f, 0.f};

        for (int k0 = 0; k0 < T_BINS; k0 += 32) {
            // 1. convert prefetched A regs (RNE), write 16B to LDS
            half8 hv;
            hv[0] = (_Float16)pa0.x; hv[1] = (_Float16)pa0.y;
            hv[2] = (_Float16)pa0.z; hv[3] = (_Float16)pa0.w;
            hv[4] = (_Float16)pa1.x; hv[5] = (_Float16)pa1.y;
            hv[6] = (_Float16)pa1.z; hv[7] = (_Float16)pa1.w;
            *(half8*)sAdst = hv;                       // ds_write_b128
            // 2. async-stage W tile (256 rows x 32 k)
#pragma unroll
            for (int r = 0; r < 4; ++r) {
                int c = r * 256 + tid;
                int wrow = c >> 2, wkc = (c & 3) * 8;
                async16h(Wh + (size_t)(bx * 256 + wrow) * T_BINS + k0 + wkc,
                         &sW[(r * 256 + wc * 64) * 8]);
            }
            // 3. prefetch next A tile (wraps to k=0 at bx boundary)
            int kn = (k0 + 32) & (T_BINS - 1);
            pa0 = *(const float4*)(Abase + kn);
            pa1 = *(const float4*)(Abase + kn + 4);
            // 4. drain staging, sync
            asm volatile("s_waitcnt vmcnt(0)" ::: "memory");
            __syncthreads();
            // 5. fragments + MFMA
            half8 ah[4], wh[4];
#pragma unroll
            for (int i = 0; i < 4; ++i)
                ah[i] = *(const half8*)&sA[(i * 16 + (lane & 15)) * 32 + ko];
#pragma unroll
            for (int j = 0; j < 4; ++j)
                wh[j] = *(const half8*)&sW[(wc * 64 + j * 16 + (lane & 15)) * 32 + ko];
#pragma unroll
            for (int i = 0; i < 4; ++i)
#pragma unroll
                for (int j = 0; j < 4; ++j)
                    acc[i][j] = __builtin_amdgcn_mfma_f32_16x16x32_f16(ah[i], wh[j], acc[i][j], 0, 0, 0);
            __syncthreads();
        }

        // running per-row argmax update (cols strictly increase over bx,j -> strict > keeps first)
#pragma unroll
        for (int i = 0; i < 4; ++i)
#pragma unroll
            for (int r = 0; r < 4; ++r)
#pragma unroll
                for (int j = 0; j < 4; ++j) {
                    float v = acc[i][j][r] + bj[j];
                    if (v > run_best[i][r]) { run_best[i][r] = v; run_col[i][r] = colbase + j * 16; }
                }
    }

    // 16-lane (column-lane) reduce; lanes {0,16,32,48} publish per-row candidates
#pragma unroll
    for (int i = 0; i < 4; ++i)
#pragma unroll
        for (int r = 0; r < 4; ++r) {
            float best = run_best[i][r];
            int   bc   = run_col[i][r];
#pragma unroll
            for (int off = 8; off >= 1; off >>= 1) {
                float ov = __shfl_xor(best, off, 64);
                int   oc = __shfl_xor(bc, off, 64);
                if (ov > best || (ov == best && oc < bc)) { best = ov; bc = oc; }
            }
            if ((lane & 15) == 0)
                cand[wc][i * 16 + (lane >> 4) * 4 + r] = pack_max(best, bc);
        }
    __syncthreads();

    // wave 0: combine 4 col-group candidates per row, write trunc_pos + loss
    if (tid < 64) {
        unsigned long long m01 = cand[0][tid] > cand[1][tid] ? cand[0][tid] : cand[1][tid];
        unsigned long long m23 = cand[2][tid] > cand[3][tid] ? cand[2][tid] : cand[3][tid];
        unsigned long long m = m01 > m23 ? m01 : m23;
        unsigned col = ~(unsigned)m;
        float p = (float)col;
        int rowG = by * 64 + tid;
        out_trunc[rowG] = p;
        trunc_s[tid] = p;
        float d = p - labels[rowG];
        float term = d * d * (1.0f / (float)B_ROWS);
#pragma unroll
        for (int off = 32; off >= 1; off >>= 1)
            term += __shfl_down(term, off, 64);
        if (tid == 0) atomicAdd(loss_acc, term);
    }
    __syncthreads();

    // scan phase: wave wc handles rows wc*16 .. wc*16+15; lane covers 16 elements
    for (int rr = 0; rr < 16; ++rr) {
        int row  = wc * 16 + rr;
        int rowG = by * 64 + row;
        const float* Hrow = A + (size_t)rowG * T_BINS + lane * 16;
        float4 h0 = *(const float4*)(Hrow + 0);
        float4 h1 = *(const float4*)(Hrow + 4);
        float4 h2 = *(const float4*)(Hrow + 8);
        float4 h3 = *(const float4*)(Hrow + 12);
        float hv[16] = {h0.x, h0.y, h0.z, h0.w, h1.x, h1.y, h1.z, h1.w,
                        h2.x, h2.y, h2.z, h2.w, h3.x, h3.y, h3.z, h3.w};
        float vprod[16];
        float run = 1.f;
#pragma unroll
        for (int j = 0; j < 16; ++j) { run *= (1.f - hv[j]); vprod[j] = run; }
        // inclusive wave scan of per-lane totals -> exclusive prefix
        float x = run;
#pragma unroll
        for (int off = 1; off < 64; off <<= 1) {
            float o = __shfl_up(x, off, 64);
            if (lane >= off) x *= o;
        }
        float pre = __shfl_up(x, 1, 64);
        if (lane == 0) pre = 1.f;

        int p  = (int)trunc_s[row];
        int t0 = lane * 16;
        float sv[16];
#pragma unroll
        for (int j = 0; j < 16; ++j) {
            float s = pre * vprod[j];
            int t = t0 + j;
            if (t >= p) s *= __expf((float)(p - t));
            sv[j] = s;
        }
        float* Srow = out_S + (size_t)rowG * T_BINS + lane * 16;
        *(float4*)(Srow + 0)  = (float4){sv[0],  sv[1],  sv[2],  sv[3]};
        *(float4*)(Srow + 4)  = (float4){sv[4],  sv[5],  sv[6],  sv[7]};
        *(float4*)(Srow + 8)  = (float4){sv[8],  sv[9],  sv[10], sv[11]};
        *(float4*)(Srow + 12) = (float4){sv[12], sv[13], sv[14], sv[15]};
    }
}

// ---------------- fp32 fallback path (round-1 kernels), used if ws too small ----------------
#define BMf 64
#define BKf 16
#define LDSS (BMf + 4)
__global__ __launch_bounds__(256) void gemm_argmax_fp32(
    const float* __restrict__ A, const float* __restrict__ W,
    const float* __restrict__ bias, unsigned long long* __restrict__ rec)
{
    __shared__ float As[BKf][LDSS];
    __shared__ float Ws[BKf][LDSS];
    const int tid = threadIdx.x;
    const int tx = tid & 15, ty = tid >> 4;
    const int bx = blockIdx.x, by = blockIdx.y;
    const int ar = tid >> 2, ak = (tid & 3) << 2;
    const float* Arow = A + (size_t)(by * BMf + ar) * T_BINS + ak;
    const float* Wrow = W + (size_t)(bx * BMf + ar) * T_BINS + ak;
    float acc[4][4];
#pragma unroll
    for (int i = 0; i < 4; ++i)
#pragma unroll
        for (int j = 0; j < 4; ++j) acc[i][j] = 0.f;
    for (int k0 = 0; k0 < T_BINS; k0 += BKf) {
        float4 av = *(const float4*)(Arow + k0);
        float4 wvv = *(const float4*)(Wrow + k0);
        As[ak + 0][ar] = av.x; As[ak + 1][ar] = av.y; As[ak + 2][ar] = av.z; As[ak + 3][ar] = av.w;
        Ws[ak + 0][ar] = wvv.x; Ws[ak + 1][ar] = wvv.y; Ws[ak + 2][ar] = wvv.z; Ws[ak + 3][ar] = wvv.w;
        __syncthreads();
#pragma unroll
        for (int k = 0; k < BKf; ++k) {
            float4 a4 = *(const float4*)&As[k][ty * 4];
            float4 w4 = *(const float4*)&Ws[k][tx * 4];
            float aa[4] = {a4.x, a4.y, a4.z, a4.w};
            float ww[4] = {w4.x, w4.y, w4.z, w4.w};
#pragma unroll
            for (int i = 0; i < 4; ++i)
#pragma unroll
                for (int j = 0; j < 4; ++j) acc[i][j] = fmaf(aa[i], ww[j], acc[i][j]);
        }
        __syncthreads();
    }
    const int colBase = bx * BMf + tx * 4;
    float bv[4];
#pragma unroll
    for (int j = 0; j < 4; ++j) bv[j] = bias[colBase + j];
#pragma unroll
    for (int i = 0; i < 4; ++i) {
        float best = acc[i][0] + bv[0];
        int bc = colBase;
#pragma unroll
        for (int j = 1; j < 4; ++j) {
            float v = acc[i][j] + bv[j];
            if (v > best) { best = v; bc = colBase + j; }
        }
#pragma unroll
        for (int off = 8; off >= 1; off >>= 1) {
            float ov = __shfl_xor(best, off, 64);
            int oc = __shfl_xor(bc, off, 64);
            if (ov > best || (ov == best && oc < bc)) { best = ov; bc = oc; }
        }
        if (tx == 0) atomicMax(&rec[by * BMf + ty * 4 + i], pack_max(best, bc));
    }
}

__global__ __launch_bounds__(256) void finalize_kernel(
    const unsigned long long* __restrict__ rec, const float* __restrict__ labels,
    float* __restrict__ out_trunc, float* __restrict__ loss_acc)
{
    int i = blockIdx.x * 256 + threadIdx.x;
    unsigned col = ~(unsigned)(rec[i] & 0xFFFFFFFFull);
    float p = (float)col;
    out_trunc[i] = p;
    float d = p - labels[i];
    float term = d * d * (1.0f / (float)B_ROWS);
#pragma unroll
    for (int off = 32; off >= 1; off >>= 1)
        term += __shfl_down(term, off, 64);
    __shared__ float partials[4];
    int lane = threadIdx.x & 63, wv = threadIdx.x >> 6;
    if (lane == 0) partials[wv] = term;
    __syncthreads();
    if (threadIdx.x == 0)
        atomicAdd(loss_acc, partials[0] + partials[1] + partials[2] + partials[3]);
}

__global__ __launch_bounds__(256) void scan_kernel_f32(
    const float* __restrict__ H, const float* __restrict__ trunc_f,
    float* __restrict__ Sout)
{
    const int row = blockIdx.x;
    const int tid = threadIdx.x;
    const int lane = tid & 63;
    const int wv = tid >> 6;
    const float4 h = *(const float4*)(H + (size_t)row * T_BINS + tid * 4);
    float l0 = 1.f - h.x;
    float l1 = l0 * (1.f - h.y);
    float l2 = l1 * (1.f - h.z);
    float l3 = l2 * (1.f - h.w);
    float x = l3;
#pragma unroll
    for (int off = 1; off < 64; off <<= 1) {
        float o = __shfl_up(x, off, 64);
        if (lane >= off) x *= o;
    }
    float ex = __shfl_up(x, 1, 64);
    if (lane == 0) ex = 1.f;
    __shared__ float wtot[4];
    if (lane == 63) wtot[wv] = x;
    __syncthreads();
    float wpre = 1.f;
#pragma unroll
    for (int w = 0; w < 3; ++w)
        if (w < wv) wpre *= wtot[w];
    float pre = wpre * ex;
    int p = (int)trunc_f[row];
    int t0 = tid * 4;
    float sv[4] = {pre * l0, pre * l1, pre * l2, pre * l3};
#pragma unroll
    for (int j = 0; j < 4; ++j) {
        int t = t0 + j;
        if (t >= p) sv[j] *= __expf((float)(p - t));
    }
    float4 s4 = {sv[0], sv[1], sv[2], sv[3]};
    *(float4*)(Sout + (size_t)row * T_BINS + tid * 4) = s4;
}

extern "C" void kernel_launch(void* const* d_in, const int* in_sizes, int n_in,
                              void* d_out, int out_size, void* d_ws, size_t ws_size,
                              hipStream_t stream)
{
    const float* hazard = (const float*)d_in[0];   // [B, T]
    const float* labels = (const float*)d_in[1];   // [B]
    const float* W      = (const float*)d_in[2];   // [T, T]
    const float* bias   = (const float*)d_in[3];   // [T]

    float* out       = (float*)d_out;
    float* out_trunc = out;                                       // B floats
    float* out_S     = out + B_ROWS;                              // B*T floats
    float* out_loss  = out + B_ROWS + (size_t)B_ROWS * T_BINS;    // 1 float

    hipMemsetAsync(out_loss, 0, sizeof(float), stream);

    const size_t NW = (size_t)T_BINS * T_BINS;
    if (ws_size >= NW * sizeof(_Float16)) {
        _Float16* Wh = (_Float16*)d_ws;
        tof16_kernel<<<(int)(NW / 4 / 256), 256, 0, stream>>>(W, Wh, (int)(NW / 4));
        mega_kernel<<<B_ROWS / 64, 256, 0, stream>>>(
            hazard, Wh, bias, labels, out_trunc, out_S, out_loss);
    } else {
        unsigned long long* rec = (unsigned long long*)out_S;
        hipMemsetAsync(rec, 0, (size_t)B_ROWS * sizeof(unsigned long long), stream);
        dim3 ggrid(T_BINS / BMf, B_ROWS / BMf);
        gemm_argmax_fp32<<<ggrid, 256, 0, stream>>>(hazard, W, bias, rec);
        finalize_kernel<<<B_ROWS / 256, 256, 0, stream>>>(rec, labels, out_trunc, out_loss);
        scan_kernel_f32<<<B_ROWS, 256, 0, stream>>>(hazard, out_trunc, out_S);
    }
}